// Round 4
// 437.961 us; speedup vs baseline: 1.0898x; 1.0898x over previous
//
#include <hip/hip_runtime.h>
#include <stdint.h>

#define NTOK 8192
#define DIM  1024
#define HID  2048
#define NE   8
#define CAP  17408   // 16384 slots + 8*128 max padding
#define TM 128
#define TN 128       // 128x128 tile = m97 structure (912 TF measured optimum)
#define TKK 64       // k elems per tile; row = 128 B (unpadded, required by global_load_lds)

typedef __bf16  bf16x8  __attribute__((ext_vector_type(8)));
typedef float   floatx4 __attribute__((ext_vector_type(4)));

__device__ __forceinline__ unsigned short f2bf(float f) {
  union { float f; unsigned u; } v; v.f = f;
  unsigned r = v.u + 0x7FFFu + ((v.u >> 16) & 1u);
  return (unsigned short)(r >> 16);
}

__device__ __forceinline__ void async_ld16(const unsigned short* g, unsigned short* l) {
  __builtin_amdgcn_global_load_lds(
      (const __attribute__((address_space(1))) unsigned int*)(const void*)g,
      (__attribute__((address_space(3))) unsigned int*)(void*)l, 16, 0, 0);
}

// fast GELU (tanh approx): x * sigmoid(2*0.7978845608*(x+0.044715 x^3))
__device__ __forceinline__ float gelu_fast(float v) {
  float g = 0.79788456080286536f * (v + 0.044715f * v * v * v);
  // sigmoid(2g) = 1/(1+exp2(-2g*log2e))
  float t = __builtin_amdgcn_exp2f(-2.8853900817779268f * g);
  return v * __builtin_amdgcn_rcpf(1.0f + t);
}

// pack 4 floats -> 4 bf16 in uint2
__device__ __forceinline__ uint2 pack4bf(float a, float b, float c, float d) {
  uint2 o;
  o.x = (unsigned)f2bf(a) | ((unsigned)f2bf(b) << 16);
  o.y = (unsigned)f2bf(c) | ((unsigned)f2bf(d) << 16);
  return o;
}

// ------- transpose + cast: src[e][R][C] fp32 -> dst[e][C][R] bf16 -------
__global__ void transpose_cast_kernel(const float* __restrict__ src,
                                      unsigned short* __restrict__ dst,
                                      int R, int C) {
  __shared__ unsigned short T[64][65];
  int e = blockIdx.z;
  const float* S = src + (size_t)e * R * C;
  unsigned short* D2 = dst + (size_t)e * R * C;
  int c0 = blockIdx.x * 64;
  int r0 = blockIdx.y * 64;
  int col = threadIdx.x & 63;
  int rr  = threadIdx.x >> 6;
#pragma unroll
  for (int i = 0; i < 16; i++) {
    int r = rr + i * 4;
    T[col][r] = f2bf(S[(size_t)(r0 + r) * C + c0 + col]);
  }
  __syncthreads();
#pragma unroll
  for (int i = 0; i < 16; i++) {
    int r = rr + i * 4;
    D2[(size_t)(c0 + r) * R + r0 + col] = T[r][col];
  }
}

// ------- gating: LDS-staged transposed Wg, fused x->bf16 cast, NO atomics -------
__global__ __launch_bounds__(256)
void gating_kernel(const float* __restrict__ x, const float* __restrict__ Wg,
                   const float* __restrict__ bg, int* __restrict__ tok_e,
                   float* __restrict__ tok_g, unsigned short* __restrict__ xb) {
  __shared__ float WgS[NE * DIM];   // transposed [e][d], 32 KB
  int tid = threadIdx.x;
#pragma unroll
  for (int j = 0; j < NE * DIM / 256; j++) {
    int i = j * 256 + tid;
    WgS[(i & 7) * DIM + (i >> 3)] = Wg[i];     // Wg is [d][e] row-major
  }
  __syncthreads();
  int wave = tid >> 6;
  int lane = tid & 63;
#pragma unroll
  for (int ti = 0; ti < 2; ti++) {
    int t = blockIdx.x * 8 + wave * 2 + ti;
    const float* xr = x + (size_t)t * DIM;
    float p[NE];
#pragma unroll
    for (int e = 0; e < NE; e++) p[e] = 0.f;
#pragma unroll
    for (int it = 0; it < DIM / 256; it++) {
      int d = (it * 64 + lane) * 4;
      float4 xv = *(const float4*)&xr[d];
      *(uint2*)&xb[(size_t)t * DIM + d] = pack4bf(xv.x, xv.y, xv.z, xv.w);
#pragma unroll
      for (int e = 0; e < NE; e++) {
        float4 wv = *(const float4*)&WgS[e * DIM + d];
        p[e] += xv.x * wv.x + xv.y * wv.y + xv.z * wv.z + xv.w * wv.w;
      }
    }
#pragma unroll
    for (int e = 0; e < NE; e++) {
#pragma unroll
      for (int off = 32; off > 0; off >>= 1) p[e] += __shfl_xor(p[e], off);
    }
    if (lane == 0) {
      float s[NE];
      float m = -1e30f;
#pragma unroll
      for (int e = 0; e < NE; e++) { s[e] = (p[e] + bg[e]) * 0.2f; m = fmaxf(m, s[e]); }
      float sum = 0.f;
#pragma unroll
      for (int e = 0; e < NE; e++) { s[e] = expf(s[e] - m); sum += s[e]; }
      float inv = 1.0f / sum;
      int i0 = 0; float v0 = -1.f;
#pragma unroll
      for (int e = 0; e < NE; e++) { float pe = s[e] * inv; if (pe > v0) { v0 = pe; i0 = e; } }
      int i1 = -1; float v1 = -1.f;
#pragma unroll
      for (int e = 0; e < NE; e++) {
        if (e == i0) continue;
        float pe = s[e] * inv; if (pe > v1) { v1 = pe; i1 = e; }
      }
      float den = v0 + v1 + 1e-9f;
      tok_e[t * 2]     = i0; tok_g[t * 2]     = v0 / den;
      tok_e[t * 2 + 1] = i1; tok_g[t * 2 + 1] = v1 / den;
    }
  }
}

// ------- count: LDS histogram, 8 global atomics per block (32 blocks) -------
__global__ __launch_bounds__(256)
void count_kernel(const int* __restrict__ tok_e, int* __restrict__ cnt) {
  __shared__ int hist[NE];
  int tid = threadIdx.x;
  if (tid < NE) hist[tid] = 0;
  __syncthreads();
  int i0 = blockIdx.x * 512 + tid;
  atomicAdd(&hist[tok_e[i0]], 1);
  atomicAdd(&hist[tok_e[i0 + 256]], 1);
  __syncthreads();
  if (tid < NE) atomicAdd(&cnt[tid], hist[tid]);
}

// ---------------- padded segment offsets ----------------
__global__ void offsets_kernel(const int* __restrict__ cnt, int* __restrict__ seg) {
  if (threadIdx.x == 0 && blockIdx.x == 0) {
    int s = 0;
    for (int e = 0; e < NE; e++) { seg[e] = s; s += ((cnt[e] + TM - 1) / TM) * TM; }
    seg[NE] = s;
  }
}

// ------- route: block-local ranks via LDS atomics, range-reserve per block -------
__global__ __launch_bounds__(256)
void route_kernel(const int* __restrict__ tok_e, const float* __restrict__ tok_g,
                  const int* __restrict__ seg, int* __restrict__ cnt2,
                  int* __restrict__ token_row, float* __restrict__ gate_row,
                  int* __restrict__ tok_pos) {
  __shared__ int hist[NE];
  __shared__ int base[NE];
  int tid = threadIdx.x;
  if (tid < NE) hist[tid] = 0;
  __syncthreads();
  int t = blockIdx.x * 256 + tid;
  int e0 = tok_e[t * 2];
  int e1 = tok_e[t * 2 + 1];
  int r0 = atomicAdd(&hist[e0], 1);   // local rank within block
  int r1 = atomicAdd(&hist[e1], 1);
  __syncthreads();
  if (tid < NE) base[tid] = atomicAdd(&cnt2[tid], hist[tid]);  // reserve range
  __syncthreads();
  int p0 = seg[e0] + base[e0] + r0;
  int p1 = seg[e1] + base[e1] + r1;
  token_row[p0] = t; gate_row[p0] = tok_g[t * 2];     tok_pos[t * 2]     = p0;
  token_row[p1] = t; gate_row[p1] = tok_g[t * 2 + 1]; tok_pos[t * 2 + 1] = p1;
}

// ---------------- GEMM1: h = gelu(x[slots] @ W1[e] + b1[e]), 128x128 tile ----------------
// m97 structure: 4 waves, each owns a 64x64 quadrant, acc[4][4] frags, BK=64.
// 32KB LDS + ~150 regs/wave -> 3 blocks/CU (launch_bounds enforces) -> 768 slots.
__global__ __launch_bounds__(256, 3)
void gemm1_kernel(const unsigned short* __restrict__ xb, const unsigned short* __restrict__ w1t,
                  const float* __restrict__ b1, const int* __restrict__ token_row,
                  const int* __restrict__ seg, const unsigned short* __restrict__ zbuf,
                  unsigned short* __restrict__ hbuf) {
  __shared__ __align__(16) unsigned short As[TM * TKK];   // 16 KB
  __shared__ __align__(16) unsigned short Bs[TN * TKK];   // 16 KB
  int row0 = blockIdx.y * TM;
  int total = seg[NE];
  if (row0 >= total) return;
  int e = 0;
  while (row0 >= seg[e + 1]) e++;
  int n0 = blockIdx.x * TN;
  int tid = threadIdx.x;
  int lane = tid & 63;
  int w = tid >> 6;             // wave 0..3
  int wm = w >> 1;              // 0..1 (row half, 64)
  int wn = w & 1;               // 0..1 (col half, 64)
  int lrow = lane >> 3;         // 0..7
  int lk   = (lane & 7) * 8;    // element offset within 64-elem row

  floatx4 zero4 = {0.f, 0.f, 0.f, 0.f};
  floatx4 acc[4][4];
#pragma unroll
  for (int a = 0; a < 4; a++)
#pragma unroll
    for (int b = 0; b < 4; b++) acc[a][b] = zero4;

  const unsigned short* w1e = w1t + (size_t)e * DIM * HID;
  const unsigned short* srcA[4];
  const unsigned short* srcB[4];
#pragma unroll
  for (int i = 0; i < 4; i++) {
    int r = w * 32 + i * 8 + lrow;
    int t = token_row[row0 + r];
    srcA[i] = (t >= 0 ? xb + (size_t)t * DIM : zbuf) + lk;
  }
#pragma unroll
  for (int i = 0; i < 4; i++) {
    int r = w * 32 + i * 8 + lrow;
    srcB[i] = w1e + (size_t)(n0 + r) * DIM + lk;
  }

  int mr = lane & 15;
  int kq = (lane >> 4) * 8;

  for (int k0 = 0; k0 < DIM; k0 += TKK) {
#pragma unroll
    for (int i = 0; i < 4; i++)
      async_ld16(srcA[i] + k0, &As[(w * 32 + i * 8 + lrow) * TKK + lk]);
#pragma unroll
    for (int i = 0; i < 4; i++)
      async_ld16(srcB[i] + k0, &Bs[(w * 32 + i * 8 + lrow) * TKK + lk]);
    __syncthreads();
#pragma unroll
    for (int kk = 0; kk < TKK; kk += 32) {
      bf16x8 af[4], bfr[4];
#pragma unroll
      for (int im = 0; im < 4; im++)
        af[im] = *(const bf16x8*)&As[(wm * 64 + im * 16 + mr) * TKK + kk + kq];
#pragma unroll
      for (int in = 0; in < 4; in++)
        bfr[in] = *(const bf16x8*)&Bs[(wn * 64 + in * 16 + mr) * TKK + kk + kq];
      // operand-swapped: D[col n'][row m'] so each lane owns 4 consecutive cols
#pragma unroll
      for (int im = 0; im < 4; im++)
#pragma unroll
        for (int in = 0; in < 4; in++)
          acc[im][in] = __builtin_amdgcn_mfma_f32_16x16x32_bf16(bfr[in], af[im], acc[im][in], 0, 0, 0);
    }
    __syncthreads();
  }
  // epilogue: lane owns row (lane&15 within im-group), 4 consecutive cols (quad*4)
  int quad = lane >> 4;
  int c16 = lane & 15;
  const float* b1e = b1 + e * HID;
#pragma unroll
  for (int im = 0; im < 4; im++) {
    int r = row0 + wm * 64 + im * 16 + c16;
#pragma unroll
    for (int in = 0; in < 4; in++) {
      int c = n0 + wn * 64 + in * 16 + quad * 4;
      float4 bias = *(const float4*)&b1e[c];
      float v0 = gelu_fast(acc[im][in][0] + bias.x);
      float v1 = gelu_fast(acc[im][in][1] + bias.y);
      float v2 = gelu_fast(acc[im][in][2] + bias.z);
      float v3 = gelu_fast(acc[im][in][3] + bias.w);
      *(uint2*)&hbuf[(size_t)r * HID + c] = pack4bf(v0, v1, v2, v3);
    }
  }
}

// ---------------- GEMM2: obuf[slot] = gate * (h @ W2[e] + b2[e]), 128x128 tile ----------------
__global__ __launch_bounds__(256, 3)
void gemm2_kernel(const unsigned short* __restrict__ hbuf, const unsigned short* __restrict__ w2t,
                  const float* __restrict__ b2, const float* __restrict__ gate_row,
                  const int* __restrict__ seg, unsigned short* __restrict__ obuf) {
  __shared__ __align__(16) unsigned short As[TM * TKK];
  __shared__ __align__(16) unsigned short Bs[TN * TKK];
  int row0 = blockIdx.y * TM;
  int total = seg[NE];
  if (row0 >= total) return;
  int e = 0;
  while (row0 >= seg[e + 1]) e++;
  int n0 = blockIdx.x * TN;
  int tid = threadIdx.x;
  int lane = tid & 63;
  int w = tid >> 6;
  int wm = w >> 1;
  int wn = w & 1;
  int lrow = lane >> 3;
  int lk   = (lane & 7) * 8;

  floatx4 zero4 = {0.f, 0.f, 0.f, 0.f};
  floatx4 acc[4][4];
#pragma unroll
  for (int a = 0; a < 4; a++)
#pragma unroll
    for (int b = 0; b < 4; b++) acc[a][b] = zero4;

  const unsigned short* w2e = w2t + (size_t)e * DIM * HID;
  const unsigned short* srcA[4];
  const unsigned short* srcB[4];
#pragma unroll
  for (int i = 0; i < 4; i++) {
    int r = w * 32 + i * 8 + lrow;
    srcA[i] = hbuf + (size_t)(row0 + r) * HID + lk;
  }
#pragma unroll
  for (int i = 0; i < 4; i++) {
    int r = w * 32 + i * 8 + lrow;
    srcB[i] = w2e + (size_t)(n0 + r) * HID + lk;
  }

  int mr = lane & 15;
  int kq = (lane >> 4) * 8;

  for (int k0 = 0; k0 < HID; k0 += TKK) {
#pragma unroll
    for (int i = 0; i < 4; i++)
      async_ld16(srcA[i] + k0, &As[(w * 32 + i * 8 + lrow) * TKK + lk]);
#pragma unroll
    for (int i = 0; i < 4; i++)
      async_ld16(srcB[i] + k0, &Bs[(w * 32 + i * 8 + lrow) * TKK + lk]);
    __syncthreads();
#pragma unroll
    for (int kk = 0; kk < TKK; kk += 32) {
      bf16x8 af[4], bfr[4];
#pragma unroll
      for (int im = 0; im < 4; im++)
        af[im] = *(const bf16x8*)&As[(wm * 64 + im * 16 + mr) * TKK + kk + kq];
#pragma unroll
      for (int in = 0; in < 4; in++)
        bfr[in] = *(const bf16x8*)&Bs[(wn * 64 + in * 16 + mr) * TKK + kk + kq];
#pragma unroll
      for (int im = 0; im < 4; im++)
#pragma unroll
        for (int in = 0; in < 4; in++)
          acc[im][in] = __builtin_amdgcn_mfma_f32_16x16x32_bf16(bfr[in], af[im], acc[im][in], 0, 0, 0);
    }
    __syncthreads();
  }
  int quad = lane >> 4;
  int c16 = lane & 15;
  const float* b2e = b2 + e * DIM;
#pragma unroll
  for (int im = 0; im < 4; im++) {
    int r = row0 + wm * 64 + im * 16 + c16;
    float gs = gate_row[r];
#pragma unroll
    for (int in = 0; in < 4; in++) {
      int c = n0 + wn * 64 + in * 16 + quad * 4;
      float4 bias = *(const float4*)&b2e[c];
      float v0 = gs * (acc[im][in][0] + bias.x);
      float v1 = gs * (acc[im][in][1] + bias.y);
      float v2 = gs * (acc[im][in][2] + bias.z);
      float v3 = gs * (acc[im][in][3] + bias.w);
      *(uint2*)&obuf[(size_t)r * DIM + c] = pack4bf(v0, v1, v2, v3);
    }
  }
}

// ---------------- combine: y[t] = obuf[pos0] + obuf[pos1] ----------------
__global__ void combine_kernel(const unsigned short* __restrict__ obuf,
                               const int* __restrict__ tok_pos,
                               float* __restrict__ y) {
  int idx = blockIdx.x * 256 + threadIdx.x;
  int t = idx >> 7;            // DIM/8 = 128 chunks per token
  int c = (idx & 127) << 3;
  int p0 = tok_pos[t * 2];
  int p1 = tok_pos[t * 2 + 1];
  uint4 a = *(const uint4*)(obuf + (size_t)p0 * DIM + c);
  uint4 b = *(const uint4*)(obuf + (size_t)p1 * DIM + c);
  float out[8];
  unsigned au[4] = {a.x, a.y, a.z, a.w};
  unsigned bu[4] = {b.x, b.y, b.z, b.w};
#pragma unroll
  for (int i = 0; i < 4; i++) {
    union { unsigned u; float f; } lo0, hi0, lo1, hi1;
    lo0.u = au[i] << 16; hi0.u = au[i] & 0xFFFF0000u;
    lo1.u = bu[i] << 16; hi1.u = bu[i] & 0xFFFF0000u;
    out[i * 2]     = lo0.f + lo1.f;
    out[i * 2 + 1] = hi0.f + hi1.f;
  }
  float* yp = y + (size_t)t * DIM + c;
  *(float4*)yp       = *(float4*)&out[0];
  *(float4*)(yp + 4) = *(float4*)&out[4];
}

// ---------------- launch ----------------
extern "C" void kernel_launch(void* const* d_in, const int* in_sizes, int n_in,
                              void* d_out, int out_size, void* d_ws, size_t ws_size,
                              hipStream_t stream) {
  const float* x  = (const float*)d_in[0];
  const float* Wg = (const float*)d_in[1];
  const float* bg = (const float*)d_in[2];
  const float* W1 = (const float*)d_in[3];
  const float* b1 = (const float*)d_in[4];
  const float* W2 = (const float*)d_in[5];
  const float* b2 = (const float*)d_in[6];
  float* y = (float*)d_out;
  char* ws = (char*)d_ws;

  constexpr size_t OFF_META = 0;                                  // cnt@0, cnt2@64, seg@128
  constexpr size_t OFF_TOKE = 256;
  constexpr size_t OFF_TOKG = OFF_TOKE + (size_t)NTOK * 2 * 4;
  constexpr size_t OFF_TPOS = OFF_TOKG + (size_t)NTOK * 2 * 4;
  constexpr size_t OFF_TROW = OFF_TPOS + (size_t)NTOK * 2 * 4;
  constexpr size_t OFF_GROW = OFF_TROW + (size_t)CAP * 4;
  constexpr size_t OFF_ZB   = OFF_GROW + (size_t)CAP * 4;
  constexpr size_t OFF_XB   = OFF_ZB  + (size_t)DIM * 2;
  constexpr size_t OFF_W1T  = OFF_XB  + (size_t)NTOK * DIM * 2;
  constexpr size_t OFF_W2T  = OFF_W1T + (size_t)NE * DIM * HID * 2;
  constexpr size_t OFF_H    = OFF_W2T + (size_t)NE * DIM * HID * 2;
  // obuf aliases xb+w1t (both dead before gemm2 runs): needs CAP*DIM*2 = 35.7MB < 50.2MB
  constexpr size_t OFF_OBUF = OFF_XB;

  int* cnt        = (int*)(ws + OFF_META);
  int* cnt2       = (int*)(ws + OFF_META + 64);
  int* seg        = (int*)(ws + OFF_META + 128);
  int* tok_e      = (int*)(ws + OFF_TOKE);
  float* tok_g    = (float*)(ws + OFF_TOKG);
  int* tok_pos    = (int*)(ws + OFF_TPOS);
  int* token_row  = (int*)(ws + OFF_TROW);
  float* gate_row = (float*)(ws + OFF_GROW);
  unsigned short* zbuf = (unsigned short*)(ws + OFF_ZB);
  unsigned short* xb   = (unsigned short*)(ws + OFF_XB);
  unsigned short* w1t  = (unsigned short*)(ws + OFF_W1T);
  unsigned short* w2t  = (unsigned short*)(ws + OFF_W2T);
  unsigned short* hbuf = (unsigned short*)(ws + OFF_H);
  unsigned short* obuf = (unsigned short*)(ws + OFF_OBUF);

  hipMemsetAsync(ws, 0, 192, stream);                       // cnt, cnt2
  hipMemsetAsync(token_row, 0xFF, (size_t)CAP * 4, stream); // token_row = -1
  hipMemsetAsync(zbuf, 0, (size_t)DIM * 2, stream);         // zero row for padding slots

  transpose_cast_kernel<<<dim3(HID / 64, DIM / 64, NE), 256, 0, stream>>>(W1, w1t, DIM, HID);
  transpose_cast_kernel<<<dim3(DIM / 64, HID / 64, NE), 256, 0, stream>>>(W2, w2t, HID, DIM);
  gating_kernel<<<NTOK / 8, 256, 0, stream>>>(x, Wg, bg, tok_e, tok_g, xb);
  count_kernel<<<NTOK * 2 / 512, 256, 0, stream>>>(tok_e, cnt);
  offsets_kernel<<<1, 64, 0, stream>>>(cnt, seg);
  route_kernel<<<NTOK / 256, 256, 0, stream>>>(tok_e, tok_g, seg, cnt2, token_row, gate_row, tok_pos);
  gemm1_kernel<<<dim3(HID / TN, CAP / TM), 256, 0, stream>>>(xb, w1t, b1, token_row, seg, zbuf, hbuf);
  gemm2_kernel<<<dim3(DIM / TN, CAP / TM), 256, 0, stream>>>(hbuf, w2t, b2, gate_row, seg, obuf);
  combine_kernel<<<NTOK * DIM / 8 / 256, 256, 0, stream>>>(obuf, tok_pos, y);
}

// Round 6
// 437.353 us; speedup vs baseline: 1.0913x; 1.0014x over previous
//
#include <hip/hip_runtime.h>
#include <stdint.h>

#define NTOK 8192
#define DIM  1024
#define HID  2048
#define NE   8
#define CAP  17408   // 16384 slots + 8*128 max padding
#define TM 128
#define TN 128       // 128x128 tile = m97 structure (912 TF measured optimum)
#define TKK 64       // k elems per tile; row = 128 B (unpadded, required by global_load_lds)

typedef __bf16  bf16x8  __attribute__((ext_vector_type(8)));
typedef float   floatx4 __attribute__((ext_vector_type(4)));

__device__ __forceinline__ unsigned short f2bf(float f) {
  union { float f; unsigned u; } v; v.f = f;
  unsigned r = v.u + 0x7FFFu + ((v.u >> 16) & 1u);
  return (unsigned short)(r >> 16);
}

__device__ __forceinline__ void async_ld16(const unsigned short* g, unsigned short* l) {
  __builtin_amdgcn_global_load_lds(
      (const __attribute__((address_space(1))) unsigned int*)(const void*)g,
      (__attribute__((address_space(3))) unsigned int*)(void*)l, 16, 0, 0);
}

// fast GELU (tanh approx): x * sigmoid(2*0.7978845608*(x+0.044715 x^3))
__device__ __forceinline__ float gelu_fast(float v) {
  float g = 0.79788456080286536f * (v + 0.044715f * v * v * v);
  float t = __builtin_amdgcn_exp2f(-2.8853900817779268f * g);
  return v * __builtin_amdgcn_rcpf(1.0f + t);
}

// pack 4 floats -> 4 bf16 in uint2
__device__ __forceinline__ uint2 pack4bf(float a, float b, float c, float d) {
  uint2 o;
  o.x = (unsigned)f2bf(a) | ((unsigned)f2bf(b) << 16);
  o.y = (unsigned)f2bf(c) | ((unsigned)f2bf(d) << 16);
  return o;
}

// ------- fused transpose+cast for BOTH W1 and W2 (z<8: W1, z>=8: W2) -------
// vectorized: float4 loads, uint4 stores. Block (0,0,0) also zeroes the meta
// block (cnt/cnt2/seg, 192B) and zbuf -> replaces all 3 hipMemsetAsync.
__global__ __launch_bounds__(256)
void transpose_all_kernel(const float* __restrict__ W1, const float* __restrict__ W2,
                          unsigned short* __restrict__ w1t, unsigned short* __restrict__ w2t,
                          int* __restrict__ meta, unsigned short* __restrict__ zbuf) {
  __shared__ unsigned short T[64][65];
  int z = blockIdx.z;
  int tid = threadIdx.x;
  if (z == 0 && blockIdx.x == 0 && blockIdx.y == 0) {
    if (tid < 48) meta[tid] = 0;                    // cnt@0, cnt2@64, seg@128
    uint2 zz = {0u, 0u};
    *(uint2*)&zbuf[tid * 4] = zz;                   // 256*8B = 2KB zero row
  }
  const float* S;
  unsigned short* D2;
  int R, C, c0, r0;
  if (z < 8) {   // W1: [e][DIM][HID] -> w1t[e][HID][DIM]
    S = W1 + (size_t)z * DIM * HID;
    D2 = w1t + (size_t)z * DIM * HID;
    R = DIM; C = HID; c0 = blockIdx.x * 64; r0 = blockIdx.y * 64;
  } else {       // W2: [e][HID][DIM] -> w2t[e][DIM][HID]
    S = W2 + (size_t)(z - 8) * DIM * HID;
    D2 = w2t + (size_t)(z - 8) * DIM * HID;
    R = HID; C = DIM; c0 = blockIdx.y * 64; r0 = blockIdx.x * 64;
  }
  int lr = tid >> 4;          // 0..15
  int lc = (tid & 15) * 4;    // 0..60
#pragma unroll
  for (int i = 0; i < 4; i++) {
    int r = lr + i * 16;
    float4 v = *(const float4*)&S[(size_t)(r0 + r) * C + c0 + lc];
    T[lc + 0][r] = f2bf(v.x);
    T[lc + 1][r] = f2bf(v.y);
    T[lc + 2][r] = f2bf(v.z);
    T[lc + 3][r] = f2bf(v.w);
  }
  __syncthreads();
  int sc = tid >> 3;          // 0..31
  int sr = (tid & 7) * 8;     // 0..56
#pragma unroll
  for (int i = 0; i < 2; i++) {
    int c = sc + i * 32;
    const unsigned short* p = &T[c][sr];
    uint4 o;
    o.x = (unsigned)p[0] | ((unsigned)p[1] << 16);
    o.y = (unsigned)p[2] | ((unsigned)p[3] << 16);
    o.z = (unsigned)p[4] | ((unsigned)p[5] << 16);
    o.w = (unsigned)p[6] | ((unsigned)p[7] << 16);
    *(uint4*)&D2[(size_t)(c0 + c) * R + r0 + sr] = o;
  }
}

// ------- gating: LDS-staged transposed Wg, fused x->bf16 cast + expert count -------
__global__ __launch_bounds__(256)
void gating_kernel(const float* __restrict__ x, const float* __restrict__ Wg,
                   const float* __restrict__ bg, int* __restrict__ tok_e,
                   float* __restrict__ tok_g, unsigned short* __restrict__ xb,
                   int* __restrict__ cnt) {
  __shared__ float WgS[NE * DIM];   // transposed [e][d], 32 KB
  __shared__ int ghist[NE];
  int tid = threadIdx.x;
  if (tid < NE) ghist[tid] = 0;
#pragma unroll
  for (int j = 0; j < NE * DIM / 256; j++) {
    int i = j * 256 + tid;
    WgS[(i & 7) * DIM + (i >> 3)] = Wg[i];     // Wg is [d][e] row-major
  }
  __syncthreads();
  int wave = tid >> 6;
  int lane = tid & 63;
#pragma unroll
  for (int ti = 0; ti < 2; ti++) {
    int t = blockIdx.x * 8 + wave * 2 + ti;
    const float* xr = x + (size_t)t * DIM;
    float p[NE];
#pragma unroll
    for (int e = 0; e < NE; e++) p[e] = 0.f;
#pragma unroll
    for (int it = 0; it < DIM / 256; it++) {
      int d = (it * 64 + lane) * 4;
      float4 xv = *(const float4*)&xr[d];
      *(uint2*)&xb[(size_t)t * DIM + d] = pack4bf(xv.x, xv.y, xv.z, xv.w);
#pragma unroll
      for (int e = 0; e < NE; e++) {
        float4 wv = *(const float4*)&WgS[e * DIM + d];
        p[e] += xv.x * wv.x + xv.y * wv.y + xv.z * wv.z + xv.w * wv.w;
      }
    }
#pragma unroll
    for (int e = 0; e < NE; e++) {
#pragma unroll
      for (int off = 32; off > 0; off >>= 1) p[e] += __shfl_xor(p[e], off);
    }
    if (lane == 0) {
      float s[NE];
      float m = -1e30f;
#pragma unroll
      for (int e = 0; e < NE; e++) { s[e] = (p[e] + bg[e]) * 0.2f; m = fmaxf(m, s[e]); }
      float sum = 0.f;
#pragma unroll
      for (int e = 0; e < NE; e++) { s[e] = expf(s[e] - m); sum += s[e]; }
      float inv = 1.0f / sum;
      int i0 = 0; float v0 = -1.f;
#pragma unroll
      for (int e = 0; e < NE; e++) { float pe = s[e] * inv; if (pe > v0) { v0 = pe; i0 = e; } }
      int i1 = -1; float v1 = -1.f;
#pragma unroll
      for (int e = 0; e < NE; e++) {
        if (e == i0) continue;
        float pe = s[e] * inv; if (pe > v1) { v1 = pe; i1 = e; }
      }
      float den = v0 + v1 + 1e-9f;
      tok_e[t * 2]     = i0; tok_g[t * 2]     = v0 / den;
      tok_e[t * 2 + 1] = i1; tok_g[t * 2 + 1] = v1 / den;
      atomicAdd(&ghist[i0], 1);
      atomicAdd(&ghist[i1], 1);
    }
  }
  __syncthreads();
  if (tid < NE) atomicAdd(&cnt[tid], ghist[tid]);
}

// ------- route (fused offsets + pad-fill): segs computed in-block from cnt -------
__global__ __launch_bounds__(256)
void route_kernel(const int* __restrict__ tok_e, const float* __restrict__ tok_g,
                  const int* __restrict__ cnt, int* __restrict__ cnt2,
                  int* __restrict__ seg_out,
                  int* __restrict__ token_row, float* __restrict__ gate_row,
                  int* __restrict__ tok_pos) {
  __shared__ int hist[NE];
  __shared__ int base[NE];
  __shared__ int segs[NE + 1];
  __shared__ int cnts[NE];
  int tid = threadIdx.x;
  if (tid < NE) { hist[tid] = 0; cnts[tid] = cnt[tid]; }
  __syncthreads();
  if (tid == 0) {
    int s = 0;
    for (int e = 0; e < NE; e++) { segs[e] = s; s += ((cnts[e] + TM - 1) / TM) * TM; }
    segs[NE] = s;
  }
  __syncthreads();
  int t = blockIdx.x * 256 + tid;
  int e0 = tok_e[t * 2];
  int e1 = tok_e[t * 2 + 1];
  int r0 = atomicAdd(&hist[e0], 1);   // local rank within block
  int r1 = atomicAdd(&hist[e1], 1);
  __syncthreads();
  if (tid < NE) base[tid] = atomicAdd(&cnt2[tid], hist[tid]);  // reserve range
  __syncthreads();
  int p0 = segs[e0] + base[e0] + r0;
  int p1 = segs[e1] + base[e1] + r1;
  token_row[p0] = t; gate_row[p0] = tok_g[t * 2];     tok_pos[t * 2]     = p0;
  token_row[p1] = t; gate_row[p1] = tok_g[t * 2 + 1]; tok_pos[t * 2 + 1] = p1;
  if (tid <= NE) seg_out[tid] = segs[tid];   // idempotent across blocks
  // pad-fill: region [segs[e]+cnt[e], segs[e+1]) is disjoint from all real-slot
  // writes -> race-free; idempotent across blocks (replaces token_row memset)
#pragma unroll
  for (int e = 0; e < NE; e++)
    for (int i = segs[e] + cnts[e] + tid; i < segs[e + 1]; i += 256) {
      token_row[i] = -1;
      gate_row[i] = 0.f;
    }
}

// ---------------- GEMM1: h = gelu(x[slots] @ W1[e] + b1[e]), 128x128 tile ----------------
// m97 structure: 4 waves, each owns a 64x64 quadrant, acc[4][4] frags, BK=64.
// 32KB LDS + ~150 regs/wave -> 3 blocks/CU (launch_bounds enforces) -> 768 slots.
__global__ __launch_bounds__(256, 3)
void gemm1_kernel(const unsigned short* __restrict__ xb, const unsigned short* __restrict__ w1t,
                  const float* __restrict__ b1, const int* __restrict__ token_row,
                  const int* __restrict__ seg, const unsigned short* __restrict__ zbuf,
                  unsigned short* __restrict__ hbuf) {
  __shared__ __align__(16) unsigned short As[TM * TKK];   // 16 KB
  __shared__ __align__(16) unsigned short Bs[TN * TKK];   // 16 KB
  int row0 = blockIdx.y * TM;
  int total = seg[NE];
  if (row0 >= total) return;
  int e = 0;
  while (row0 >= seg[e + 1]) e++;
  int n0 = blockIdx.x * TN;
  int tid = threadIdx.x;
  int lane = tid & 63;
  int w = tid >> 6;             // wave 0..3
  int wm = w >> 1;              // 0..1 (row half, 64)
  int wn = w & 1;               // 0..1 (col half, 64)
  int lrow = lane >> 3;         // 0..7
  int lk   = (lane & 7) * 8;    // element offset within 64-elem row

  floatx4 zero4 = {0.f, 0.f, 0.f, 0.f};
  floatx4 acc[4][4];
#pragma unroll
  for (int a = 0; a < 4; a++)
#pragma unroll
    for (int b = 0; b < 4; b++) acc[a][b] = zero4;

  const unsigned short* w1e = w1t + (size_t)e * DIM * HID;
  const unsigned short* srcA[4];
  const unsigned short* srcB[4];
#pragma unroll
  for (int i = 0; i < 4; i++) {
    int r = w * 32 + i * 8 + lrow;
    int t = token_row[row0 + r];
    srcA[i] = (t >= 0 ? xb + (size_t)t * DIM : zbuf) + lk;
  }
#pragma unroll
  for (int i = 0; i < 4; i++) {
    int r = w * 32 + i * 8 + lrow;
    srcB[i] = w1e + (size_t)(n0 + r) * DIM + lk;
  }

  int mr = lane & 15;
  int kq = (lane >> 4) * 8;

  for (int k0 = 0; k0 < DIM; k0 += TKK) {
#pragma unroll
    for (int i = 0; i < 4; i++)
      async_ld16(srcA[i] + k0, &As[(w * 32 + i * 8 + lrow) * TKK + lk]);
#pragma unroll
    for (int i = 0; i < 4; i++)
      async_ld16(srcB[i] + k0, &Bs[(w * 32 + i * 8 + lrow) * TKK + lk]);
    __syncthreads();
#pragma unroll
    for (int kk = 0; kk < TKK; kk += 32) {
      bf16x8 af[4], bfr[4];
#pragma unroll
      for (int im = 0; im < 4; im++)
        af[im] = *(const bf16x8*)&As[(wm * 64 + im * 16 + mr) * TKK + kk + kq];
#pragma unroll
      for (int in = 0; in < 4; in++)
        bfr[in] = *(const bf16x8*)&Bs[(wn * 64 + in * 16 + mr) * TKK + kk + kq];
      // operand-swapped: D[col n'][row m'] so each lane owns 4 consecutive cols
#pragma unroll
      for (int im = 0; im < 4; im++)
#pragma unroll
        for (int in = 0; in < 4; in++)
          acc[im][in] = __builtin_amdgcn_mfma_f32_16x16x32_bf16(bfr[in], af[im], acc[im][in], 0, 0, 0);
    }
    __syncthreads();
  }
  // epilogue: lane owns row (lane&15 within im-group), 4 consecutive cols (quad*4)
  int quad = lane >> 4;
  int c16 = lane & 15;
  const float* b1e = b1 + e * HID;
#pragma unroll
  for (int im = 0; im < 4; im++) {
    int r = row0 + wm * 64 + im * 16 + c16;
#pragma unroll
    for (int in = 0; in < 4; in++) {
      int c = n0 + wn * 64 + in * 16 + quad * 4;
      float4 bias = *(const float4*)&b1e[c];
      float v0 = gelu_fast(acc[im][in][0] + bias.x);
      float v1 = gelu_fast(acc[im][in][1] + bias.y);
      float v2 = gelu_fast(acc[im][in][2] + bias.z);
      float v3 = gelu_fast(acc[im][in][3] + bias.w);
      *(uint2*)&hbuf[(size_t)r * HID + c] = pack4bf(v0, v1, v2, v3);
    }
  }
}

// ---------------- GEMM2: obuf[slot] = gate * (h @ W2[e] + b2[e]), 128x128 tile ----------------
__global__ __launch_bounds__(256, 3)
void gemm2_kernel(const unsigned short* __restrict__ hbuf, const unsigned short* __restrict__ w2t,
                  const float* __restrict__ b2, const float* __restrict__ gate_row,
                  const int* __restrict__ seg, unsigned short* __restrict__ obuf) {
  __shared__ __align__(16) unsigned short As[TM * TKK];
  __shared__ __align__(16) unsigned short Bs[TN * TKK];
  int row0 = blockIdx.y * TM;
  int total = seg[NE];
  if (row0 >= total) return;
  int e = 0;
  while (row0 >= seg[e + 1]) e++;
  int n0 = blockIdx.x * TN;
  int tid = threadIdx.x;
  int lane = tid & 63;
  int w = tid >> 6;
  int wm = w >> 1;
  int wn = w & 1;
  int lrow = lane >> 3;
  int lk   = (lane & 7) * 8;

  floatx4 zero4 = {0.f, 0.f, 0.f, 0.f};
  floatx4 acc[4][4];
#pragma unroll
  for (int a = 0; a < 4; a++)
#pragma unroll
    for (int b = 0; b < 4; b++) acc[a][b] = zero4;

  const unsigned short* w2e = w2t + (size_t)e * DIM * HID;
  const unsigned short* srcA[4];
  const unsigned short* srcB[4];
#pragma unroll
  for (int i = 0; i < 4; i++) {
    int r = w * 32 + i * 8 + lrow;
    srcA[i] = hbuf + (size_t)(row0 + r) * HID + lk;
  }
#pragma unroll
  for (int i = 0; i < 4; i++) {
    int r = w * 32 + i * 8 + lrow;
    srcB[i] = w2e + (size_t)(n0 + r) * HID + lk;
  }

  int mr = lane & 15;
  int kq = (lane >> 4) * 8;

  for (int k0 = 0; k0 < HID; k0 += TKK) {
#pragma unroll
    for (int i = 0; i < 4; i++)
      async_ld16(srcA[i] + k0, &As[(w * 32 + i * 8 + lrow) * TKK + lk]);
#pragma unroll
    for (int i = 0; i < 4; i++)
      async_ld16(srcB[i] + k0, &Bs[(w * 32 + i * 8 + lrow) * TKK + lk]);
    __syncthreads();
#pragma unroll
    for (int kk = 0; kk < TKK; kk += 32) {
      bf16x8 af[4], bfr[4];
#pragma unroll
      for (int im = 0; im < 4; im++)
        af[im] = *(const bf16x8*)&As[(wm * 64 + im * 16 + mr) * TKK + kk + kq];
#pragma unroll
      for (int in = 0; in < 4; in++)
        bfr[in] = *(const bf16x8*)&Bs[(wn * 64 + in * 16 + mr) * TKK + kk + kq];
#pragma unroll
      for (int im = 0; im < 4; im++)
#pragma unroll
        for (int in = 0; in < 4; in++)
          acc[im][in] = __builtin_amdgcn_mfma_f32_16x16x32_bf16(bfr[in], af[im], acc[im][in], 0, 0, 0);
    }
    __syncthreads();
  }
  int quad = lane >> 4;
  int c16 = lane & 15;
  const float* b2e = b2 + e * DIM;
#pragma unroll
  for (int im = 0; im < 4; im++) {
    int r = row0 + wm * 64 + im * 16 + c16;
    float gs = gate_row[r];
#pragma unroll
    for (int in = 0; in < 4; in++) {
      int c = n0 + wn * 64 + in * 16 + quad * 4;
      float4 bias = *(const float4*)&b2e[c];
      float v0 = gs * (acc[im][in][0] + bias.x);
      float v1 = gs * (acc[im][in][1] + bias.y);
      float v2 = gs * (acc[im][in][2] + bias.z);
      float v3 = gs * (acc[im][in][3] + bias.w);
      *(uint2*)&obuf[(size_t)r * DIM + c] = pack4bf(v0, v1, v2, v3);
    }
  }
}

// ---------------- combine: y[t] = obuf[pos0] + obuf[pos1] ----------------
__global__ void combine_kernel(const unsigned short* __restrict__ obuf,
                               const int* __restrict__ tok_pos,
                               float* __restrict__ y) {
  int idx = blockIdx.x * 256 + threadIdx.x;
  int t = idx >> 7;            // DIM/8 = 128 chunks per token
  int c = (idx & 127) << 3;
  int p0 = tok_pos[t * 2];
  int p1 = tok_pos[t * 2 + 1];
  uint4 a = *(const uint4*)(obuf + (size_t)p0 * DIM + c);
  uint4 b = *(const uint4*)(obuf + (size_t)p1 * DIM + c);
  float out[8];
  unsigned au[4] = {a.x, a.y, a.z, a.w};
  unsigned bu[4] = {b.x, b.y, b.z, b.w};
#pragma unroll
  for (int i = 0; i < 4; i++) {
    union { unsigned u; float f; } lo0, hi0, lo1, hi1;
    lo0.u = au[i] << 16; hi0.u = au[i] & 0xFFFF0000u;
    lo1.u = bu[i] << 16; hi1.u = bu[i] & 0xFFFF0000u;
    out[i * 2]     = lo0.f + lo1.f;
    out[i * 2 + 1] = hi0.f + hi1.f;
  }
  float* yp = y + (size_t)t * DIM + c;
  *(float4*)yp       = *(float4*)&out[0];
  *(float4*)(yp + 4) = *(float4*)&out[4];
}

// ---------------- launch: 6 dispatches (was 12) ----------------
extern "C" void kernel_launch(void* const* d_in, const int* in_sizes, int n_in,
                              void* d_out, int out_size, void* d_ws, size_t ws_size,
                              hipStream_t stream) {
  const float* x  = (const float*)d_in[0];
  const float* Wg = (const float*)d_in[1];
  const float* bg = (const float*)d_in[2];
  const float* W1 = (const float*)d_in[3];
  const float* b1 = (const float*)d_in[4];
  const float* W2 = (const float*)d_in[5];
  const float* b2 = (const float*)d_in[6];
  float* y = (float*)d_out;
  char* ws = (char*)d_ws;

  constexpr size_t OFF_META = 0;                                  // cnt@0, cnt2@64, seg@128
  constexpr size_t OFF_TOKE = 256;
  constexpr size_t OFF_TOKG = OFF_TOKE + (size_t)NTOK * 2 * 4;
  constexpr size_t OFF_TPOS = OFF_TOKG + (size_t)NTOK * 2 * 4;
  constexpr size_t OFF_TROW = OFF_TPOS + (size_t)NTOK * 2 * 4;
  constexpr size_t OFF_GROW = OFF_TROW + (size_t)CAP * 4;
  constexpr size_t OFF_ZB   = OFF_GROW + (size_t)CAP * 4;
  constexpr size_t OFF_XB   = OFF_ZB  + (size_t)DIM * 2;
  constexpr size_t OFF_W1T  = OFF_XB  + (size_t)NTOK * DIM * 2;
  constexpr size_t OFF_W2T  = OFF_W1T + (size_t)NE * DIM * HID * 2;
  constexpr size_t OFF_H    = OFF_W2T + (size_t)NE * DIM * HID * 2;
  // obuf aliases xb+w1t (both dead before gemm2 runs): needs CAP*DIM*2 = 35.7MB < 50.2MB
  constexpr size_t OFF_OBUF = OFF_XB;

  int* cnt        = (int*)(ws + OFF_META);
  int* cnt2       = (int*)(ws + OFF_META + 64);
  int* seg        = (int*)(ws + OFF_META + 128);
  int* tok_e      = (int*)(ws + OFF_TOKE);
  float* tok_g    = (float*)(ws + OFF_TOKG);
  int* tok_pos    = (int*)(ws + OFF_TPOS);
  int* token_row  = (int*)(ws + OFF_TROW);
  float* gate_row = (float*)(ws + OFF_GROW);
  unsigned short* zbuf = (unsigned short*)(ws + OFF_ZB);
  unsigned short* xb   = (unsigned short*)(ws + OFF_XB);
  unsigned short* w1t  = (unsigned short*)(ws + OFF_W1T);
  unsigned short* w2t  = (unsigned short*)(ws + OFF_W2T);
  unsigned short* hbuf = (unsigned short*)(ws + OFF_H);
  unsigned short* obuf = (unsigned short*)(ws + OFF_OBUF);

  // transpose_all zeroes meta+zbuf; route pad-fills token_row/gate_row -> no memsets
  transpose_all_kernel<<<dim3(32, 16, 16), 256, 0, stream>>>(W1, W2, w1t, w2t, (int*)(ws + OFF_META), zbuf);
  gating_kernel<<<NTOK / 8, 256, 0, stream>>>(x, Wg, bg, tok_e, tok_g, xb, cnt);
  route_kernel<<<NTOK / 256, 256, 0, stream>>>(tok_e, tok_g, cnt, cnt2, seg, token_row, gate_row, tok_pos);
  gemm1_kernel<<<dim3(HID / TN, CAP / TM), 256, 0, stream>>>(xb, w1t, b1, token_row, seg, zbuf, hbuf);
  gemm2_kernel<<<dim3(DIM / TN, CAP / TM), 256, 0, stream>>>(hbuf, w2t, b2, gate_row, seg, obuf);
  combine_kernel<<<NTOK * DIM / 8 / 256, 256, 0, stream>>>(obuf, tok_pos, y);
}

// Round 7
// 432.022 us; speedup vs baseline: 1.1048x; 1.0123x over previous
//
#include <hip/hip_runtime.h>
#include <stdint.h>

#define NTOK 8192
#define DIM  1024
#define HID  2048
#define NE   8
#define CAP  17408   // 16384 slots + 8*128 max padding
#define TM 128
#define TN 128       // 128x128 tile = m97 structure (912 TF measured optimum)
#define TKK 64       // k elems per tile; row = 128 B (unpadded, required by global_load_lds)

typedef __bf16  bf16x8  __attribute__((ext_vector_type(8)));
typedef float   floatx4 __attribute__((ext_vector_type(4)));

__device__ __forceinline__ unsigned short f2bf(float f) {
  union { float f; unsigned u; } v; v.f = f;
  unsigned r = v.u + 0x7FFFu + ((v.u >> 16) & 1u);
  return (unsigned short)(r >> 16);
}

__device__ __forceinline__ void async_ld16(const unsigned short* g, unsigned short* l) {
  __builtin_amdgcn_global_load_lds(
      (const __attribute__((address_space(1))) unsigned int*)(const void*)g,
      (__attribute__((address_space(3))) unsigned int*)(void*)l, 16, 0, 0);
}

// fast GELU (tanh approx): x * sigmoid(2*0.7978845608*(x+0.044715 x^3))
__device__ __forceinline__ float gelu_fast(float v) {
  float g = 0.79788456080286536f * (v + 0.044715f * v * v * v);
  float t = __builtin_amdgcn_exp2f(-2.8853900817779268f * g);
  return v * __builtin_amdgcn_rcpf(1.0f + t);
}

// pack 4 floats -> 4 bf16 in uint2 (memory order a,b,c,d)
__device__ __forceinline__ uint2 pack4bf(float a, float b, float c, float d) {
  uint2 o;
  o.x = (unsigned)f2bf(a) | ((unsigned)f2bf(b) << 16);
  o.y = (unsigned)f2bf(c) | ((unsigned)f2bf(d) << 16);
  return o;
}

// ---- transpose one 64x64 tile: S[R][C] fp32 -> D2[C][R] bf16 ----
// Register 4x4 transpose => LDS ops per thread: 4x ds_write_b64 + 2x ds_read_b128
// (was 16x write_u16 + 16x read_u16 => LDS-issue-bound). 16B-XOR swizzle on the
// row-offset (bits 4-6) keeps b128 reads aligned and spreads banks; involution,
// byte order within 16B block preserved (r*2 bits 1-3 untouched).
__device__ __forceinline__ void transpose_tile64(const float* S, unsigned short* D2,
                                                 int R, int C, int r0, int c0,
                                                 unsigned short* Ts, int tid) {
  int rr = tid >> 4;          // 0..15 -> 4-row group
  int cc = (tid & 15) * 4;    // 4-col group
  float4 v0 = *(const float4*)&S[(size_t)(r0 + rr * 4 + 0) * C + c0 + cc];
  float4 v1 = *(const float4*)&S[(size_t)(r0 + rr * 4 + 1) * C + c0 + cc];
  float4 v2 = *(const float4*)&S[(size_t)(r0 + rr * 4 + 2) * C + c0 + cc];
  float4 v3 = *(const float4*)&S[(size_t)(r0 + rr * 4 + 3) * C + c0 + cc];
  // per col j: 4 row-values packed (8B), T[col][rr*4..rr*4+3]
  uint2 p0 = pack4bf(v0.x, v1.x, v2.x, v3.x);
  uint2 p1 = pack4bf(v0.y, v1.y, v2.y, v3.y);
  uint2 p2 = pack4bf(v0.z, v1.z, v2.z, v3.z);
  uint2 p3 = pack4bf(v0.w, v1.w, v2.w, v3.w);
  char* tb = (char*)Ts;
  int rb = rr * 8;            // byte offset of row group within col (bits 3-6)
#pragma unroll
  for (int j = 0; j < 4; j++) {
    int col = cc + j;
    uint2 pj = j == 0 ? p0 : j == 1 ? p1 : j == 2 ? p2 : p3;
    *(uint2*)(tb + col * 128 + (rb ^ ((col & 7) << 4))) = pj;
  }
  __syncthreads();
  int sr = (tid & 7) * 8;     // row start, mult of 8 -> sr*2 has only bits 4-6
#pragma unroll
  for (int i = 0; i < 2; i++) {
    int col = (tid >> 3) + i * 32;
    uint4 o = *(const uint4*)(tb + col * 128 + ((sr * 2) ^ ((col & 7) << 4)));
    *(uint4*)&D2[(size_t)(c0 + col) * R + r0 + sr] = o;
  }
}

// ------- prep: W1+W2 transpose-cast AND gating in ONE dispatch -------
// bid 0..1023: gating (indep of transposes); 1024..5119: W1; 5120..9215: W2.
// Transpose is LDS-issue/latency-bound, gating BW-light -> co-residency overlaps.
// cnt/cnt2 are zeroed by a hipMemsetAsync BEFORE this dispatch (same-dispatch
// zeroing would race gating's atomicAdd). zbuf zeroed by first W1 block.
__global__ __launch_bounds__(256)
void prep_kernel(const float* __restrict__ x, const float* __restrict__ Wg,
                 const float* __restrict__ bg, const float* __restrict__ W1,
                 const float* __restrict__ W2,
                 unsigned short* __restrict__ w1t, unsigned short* __restrict__ w2t,
                 int* __restrict__ tok_e, float* __restrict__ tok_g,
                 unsigned short* __restrict__ xb, int* __restrict__ cnt,
                 unsigned short* __restrict__ zbuf) {
  __shared__ __align__(16) char smem[NE * DIM * 4];   // 32 KB, union of uses
  __shared__ int ghist[NE];
  int bid = blockIdx.x;
  int tid = threadIdx.x;

  if (bid >= 1024) {
    // ---------------- transpose part ----------------
    unsigned short* Ts = (unsigned short*)smem;       // 8 KB used
    int tz = bid - 1024;
    if (tz < 4096) {      // W1: [e][DIM][HID] -> w1t[e][HID][DIM]
      if (tz == 0) { uint2 zz = {0u, 0u}; *(uint2*)&zbuf[tid * 4] = zz; }
      int e = tz >> 9, t = tz & 511;
      int c0 = (t & 31) * 64, r0 = (t >> 5) * 64;     // c over HID(32), r over DIM(16)
      transpose_tile64(W1 + (size_t)e * DIM * HID, w1t + (size_t)e * DIM * HID,
                       DIM, HID, r0, c0, Ts, tid);
    } else {              // W2: [e][HID][DIM] -> w2t[e][DIM][HID]
      int tz2 = tz - 4096;
      int e = tz2 >> 9, t = tz2 & 511;
      int r0 = (t & 31) * 64, c0 = (t >> 5) * 64;     // r over HID(32), c over DIM(16)
      transpose_tile64(W2 + (size_t)e * DIM * HID, w2t + (size_t)e * DIM * HID,
                       HID, DIM, r0, c0, Ts, tid);
    }
    return;
  }

  // ---------------- gating part (block g = bid) ----------------
  float* WgS = (float*)smem;                          // [e][d] transposed, 32 KB
  if (tid < NE) ghist[tid] = 0;
#pragma unroll
  for (int j = 0; j < NE * DIM / 256; j++) {
    int i = j * 256 + tid;
    WgS[(i & 7) * DIM + (i >> 3)] = Wg[i];            // Wg is [d][e] row-major
  }
  __syncthreads();
  int wave = tid >> 6;
  int lane = tid & 63;
#pragma unroll
  for (int ti = 0; ti < 2; ti++) {
    int t = bid * 8 + wave * 2 + ti;
    const float* xr = x + (size_t)t * DIM;
    float p[NE];
#pragma unroll
    for (int e = 0; e < NE; e++) p[e] = 0.f;
#pragma unroll
    for (int it = 0; it < DIM / 256; it++) {
      int d = (it * 64 + lane) * 4;
      float4 xv = *(const float4*)&xr[d];
      *(uint2*)&xb[(size_t)t * DIM + d] = pack4bf(xv.x, xv.y, xv.z, xv.w);
#pragma unroll
      for (int e = 0; e < NE; e++) {
        float4 wv = *(const float4*)&WgS[e * DIM + d];
        p[e] += xv.x * wv.x + xv.y * wv.y + xv.z * wv.z + xv.w * wv.w;
      }
    }
#pragma unroll
    for (int e = 0; e < NE; e++) {
#pragma unroll
      for (int off = 32; off > 0; off >>= 1) p[e] += __shfl_xor(p[e], off);
    }
    if (lane == 0) {
      float s[NE];
      float m = -1e30f;
#pragma unroll
      for (int e = 0; e < NE; e++) { s[e] = (p[e] + bg[e]) * 0.2f; m = fmaxf(m, s[e]); }
      float sum = 0.f;
#pragma unroll
      for (int e = 0; e < NE; e++) { s[e] = expf(s[e] - m); sum += s[e]; }
      float inv = 1.0f / sum;
      int i0 = 0; float v0 = -1.f;
#pragma unroll
      for (int e = 0; e < NE; e++) { float pe = s[e] * inv; if (pe > v0) { v0 = pe; i0 = e; } }
      int i1 = -1; float v1 = -1.f;
#pragma unroll
      for (int e = 0; e < NE; e++) {
        if (e == i0) continue;
        float pe = s[e] * inv; if (pe > v1) { v1 = pe; i1 = e; }
      }
      float den = v0 + v1 + 1e-9f;
      tok_e[t * 2]     = i0; tok_g[t * 2]     = v0 / den;
      tok_e[t * 2 + 1] = i1; tok_g[t * 2 + 1] = v1 / den;
      atomicAdd(&ghist[i0], 1);
      atomicAdd(&ghist[i1], 1);
    }
  }
  __syncthreads();
  if (tid < NE) atomicAdd(&cnt[tid], ghist[tid]);
}

// ------- route (fused offsets + pad-fill): segs computed in-block from cnt -------
__global__ __launch_bounds__(256)
void route_kernel(const int* __restrict__ tok_e, const float* __restrict__ tok_g,
                  const int* __restrict__ cnt, int* __restrict__ cnt2,
                  int* __restrict__ seg_out,
                  int* __restrict__ token_row, float* __restrict__ gate_row,
                  int* __restrict__ tok_pos) {
  __shared__ int hist[NE];
  __shared__ int base[NE];
  __shared__ int segs[NE + 1];
  __shared__ int cnts[NE];
  int tid = threadIdx.x;
  if (tid < NE) { hist[tid] = 0; cnts[tid] = cnt[tid]; }
  __syncthreads();
  if (tid == 0) {
    int s = 0;
    for (int e = 0; e < NE; e++) { segs[e] = s; s += ((cnts[e] + TM - 1) / TM) * TM; }
    segs[NE] = s;
  }
  __syncthreads();
  int t = blockIdx.x * 256 + tid;
  int e0 = tok_e[t * 2];
  int e1 = tok_e[t * 2 + 1];
  int r0 = atomicAdd(&hist[e0], 1);   // local rank within block
  int r1 = atomicAdd(&hist[e1], 1);
  __syncthreads();
  if (tid < NE) base[tid] = atomicAdd(&cnt2[tid], hist[tid]);  // reserve range
  __syncthreads();
  int p0 = segs[e0] + base[e0] + r0;
  int p1 = segs[e1] + base[e1] + r1;
  token_row[p0] = t; gate_row[p0] = tok_g[t * 2];     tok_pos[t * 2]     = p0;
  token_row[p1] = t; gate_row[p1] = tok_g[t * 2 + 1]; tok_pos[t * 2 + 1] = p1;
  if (tid <= NE) seg_out[tid] = segs[tid];   // idempotent across blocks
  // pad-fill: [segs[e]+cnt[e], segs[e+1]) disjoint from real-slot writes ->
  // race-free; idempotent across blocks (replaces token_row memset)
#pragma unroll
  for (int e = 0; e < NE; e++)
    for (int i = segs[e] + cnts[e] + tid; i < segs[e + 1]; i += 256) {
      token_row[i] = -1;
      gate_row[i] = 0.f;
    }
}

// ---------------- GEMM1: h = gelu(x[slots] @ W1[e] + b1[e]), 128x128 tile ----------------
// m97 structure: 4 waves, each owns a 64x64 quadrant, acc[4][4] frags, BK=64.
// 32KB LDS + ~150 regs/wave -> 3 blocks/CU -> 768 slots. (CONTROL: unchanged)
__global__ __launch_bounds__(256, 3)
void gemm1_kernel(const unsigned short* __restrict__ xb, const unsigned short* __restrict__ w1t,
                  const float* __restrict__ b1, const int* __restrict__ token_row,
                  const int* __restrict__ seg, const unsigned short* __restrict__ zbuf,
                  unsigned short* __restrict__ hbuf) {
  __shared__ __align__(16) unsigned short As[TM * TKK];   // 16 KB
  __shared__ __align__(16) unsigned short Bs[TN * TKK];   // 16 KB
  int row0 = blockIdx.y * TM;
  int total = seg[NE];
  if (row0 >= total) return;
  int e = 0;
  while (row0 >= seg[e + 1]) e++;
  int n0 = blockIdx.x * TN;
  int tid = threadIdx.x;
  int lane = tid & 63;
  int w = tid >> 6;             // wave 0..3
  int wm = w >> 1;              // 0..1 (row half, 64)
  int wn = w & 1;               // 0..1 (col half, 64)
  int lrow = lane >> 3;         // 0..7
  int lk   = (lane & 7) * 8;    // element offset within 64-elem row

  floatx4 zero4 = {0.f, 0.f, 0.f, 0.f};
  floatx4 acc[4][4];
#pragma unroll
  for (int a = 0; a < 4; a++)
#pragma unroll
    for (int b = 0; b < 4; b++) acc[a][b] = zero4;

  const unsigned short* w1e = w1t + (size_t)e * DIM * HID;
  const unsigned short* srcA[4];
  const unsigned short* srcB[4];
#pragma unroll
  for (int i = 0; i < 4; i++) {
    int r = w * 32 + i * 8 + lrow;
    int t = token_row[row0 + r];
    srcA[i] = (t >= 0 ? xb + (size_t)t * DIM : zbuf) + lk;
  }
#pragma unroll
  for (int i = 0; i < 4; i++) {
    int r = w * 32 + i * 8 + lrow;
    srcB[i] = w1e + (size_t)(n0 + r) * DIM + lk;
  }

  int mr = lane & 15;
  int kq = (lane >> 4) * 8;

  for (int k0 = 0; k0 < DIM; k0 += TKK) {
#pragma unroll
    for (int i = 0; i < 4; i++)
      async_ld16(srcA[i] + k0, &As[(w * 32 + i * 8 + lrow) * TKK + lk]);
#pragma unroll
    for (int i = 0; i < 4; i++)
      async_ld16(srcB[i] + k0, &Bs[(w * 32 + i * 8 + lrow) * TKK + lk]);
    __syncthreads();
#pragma unroll
    for (int kk = 0; kk < TKK; kk += 32) {
      bf16x8 af[4], bfr[4];
#pragma unroll
      for (int im = 0; im < 4; im++)
        af[im] = *(const bf16x8*)&As[(wm * 64 + im * 16 + mr) * TKK + kk + kq];
#pragma unroll
      for (int in = 0; in < 4; in++)
        bfr[in] = *(const bf16x8*)&Bs[(wn * 64 + in * 16 + mr) * TKK + kk + kq];
      // operand-swapped: D[col n'][row m'] so each lane owns 4 consecutive cols
#pragma unroll
      for (int im = 0; im < 4; im++)
#pragma unroll
        for (int in = 0; in < 4; in++)
          acc[im][in] = __builtin_amdgcn_mfma_f32_16x16x32_bf16(bfr[in], af[im], acc[im][in], 0, 0, 0);
    }
    __syncthreads();
  }
  // epilogue: lane owns row (lane&15 within im-group), 4 consecutive cols (quad*4)
  int quad = lane >> 4;
  int c16 = lane & 15;
  const float* b1e = b1 + e * HID;
#pragma unroll
  for (int im = 0; im < 4; im++) {
    int r = row0 + wm * 64 + im * 16 + c16;
#pragma unroll
    for (int in = 0; in < 4; in++) {
      int c = n0 + wn * 64 + in * 16 + quad * 4;
      float4 bias = *(const float4*)&b1e[c];
      float v0 = gelu_fast(acc[im][in][0] + bias.x);
      float v1 = gelu_fast(acc[im][in][1] + bias.y);
      float v2 = gelu_fast(acc[im][in][2] + bias.z);
      float v3 = gelu_fast(acc[im][in][3] + bias.w);
      *(uint2*)&hbuf[(size_t)r * HID + c] = pack4bf(v0, v1, v2, v3);
    }
  }
}

// ---------------- GEMM2: obuf[slot] = gate * (h @ W2[e] + b2[e]), 128x128 tile ----------------
// (CONTROL: unchanged)
__global__ __launch_bounds__(256, 3)
void gemm2_kernel(const unsigned short* __restrict__ hbuf, const unsigned short* __restrict__ w2t,
                  const float* __restrict__ b2, const float* __restrict__ gate_row,
                  const int* __restrict__ seg, unsigned short* __restrict__ obuf) {
  __shared__ __align__(16) unsigned short As[TM * TKK];
  __shared__ __align__(16) unsigned short Bs[TN * TKK];
  int row0 = blockIdx.y * TM;
  int total = seg[NE];
  if (row0 >= total) return;
  int e = 0;
  while (row0 >= seg[e + 1]) e++;
  int n0 = blockIdx.x * TN;
  int tid = threadIdx.x;
  int lane = tid & 63;
  int w = tid >> 6;
  int wm = w >> 1;
  int wn = w & 1;
  int lrow = lane >> 3;
  int lk   = (lane & 7) * 8;

  floatx4 zero4 = {0.f, 0.f, 0.f, 0.f};
  floatx4 acc[4][4];
#pragma unroll
  for (int a = 0; a < 4; a++)
#pragma unroll
    for (int b = 0; b < 4; b++) acc[a][b] = zero4;

  const unsigned short* w2e = w2t + (size_t)e * DIM * HID;
  const unsigned short* srcA[4];
  const unsigned short* srcB[4];
#pragma unroll
  for (int i = 0; i < 4; i++) {
    int r = w * 32 + i * 8 + lrow;
    srcA[i] = hbuf + (size_t)(row0 + r) * HID + lk;
  }
#pragma unroll
  for (int i = 0; i < 4; i++) {
    int r = w * 32 + i * 8 + lrow;
    srcB[i] = w2e + (size_t)(n0 + r) * HID + lk;
  }

  int mr = lane & 15;
  int kq = (lane >> 4) * 8;

  for (int k0 = 0; k0 < HID; k0 += TKK) {
#pragma unroll
    for (int i = 0; i < 4; i++)
      async_ld16(srcA[i] + k0, &As[(w * 32 + i * 8 + lrow) * TKK + lk]);
#pragma unroll
    for (int i = 0; i < 4; i++)
      async_ld16(srcB[i] + k0, &Bs[(w * 32 + i * 8 + lrow) * TKK + lk]);
    __syncthreads();
#pragma unroll
    for (int kk = 0; kk < TKK; kk += 32) {
      bf16x8 af[4], bfr[4];
#pragma unroll
      for (int im = 0; im < 4; im++)
        af[im] = *(const bf16x8*)&As[(wm * 64 + im * 16 + mr) * TKK + kk + kq];
#pragma unroll
      for (int in = 0; in < 4; in++)
        bfr[in] = *(const bf16x8*)&Bs[(wn * 64 + in * 16 + mr) * TKK + kk + kq];
#pragma unroll
      for (int im = 0; im < 4; im++)
#pragma unroll
        for (int in = 0; in < 4; in++)
          acc[im][in] = __builtin_amdgcn_mfma_f32_16x16x32_bf16(bfr[in], af[im], acc[im][in], 0, 0, 0);
    }
    __syncthreads();
  }
  int quad = lane >> 4;
  int c16 = lane & 15;
  const float* b2e = b2 + e * DIM;
#pragma unroll
  for (int im = 0; im < 4; im++) {
    int r = row0 + wm * 64 + im * 16 + c16;
    float gs = gate_row[r];
#pragma unroll
    for (int in = 0; in < 4; in++) {
      int c = n0 + wn * 64 + in * 16 + quad * 4;
      float4 bias = *(const float4*)&b2e[c];
      float v0 = gs * (acc[im][in][0] + bias.x);
      float v1 = gs * (acc[im][in][1] + bias.y);
      float v2 = gs * (acc[im][in][2] + bias.z);
      float v3 = gs * (acc[im][in][3] + bias.w);
      *(uint2*)&obuf[(size_t)r * DIM + c] = pack4bf(v0, v1, v2, v3);
    }
  }
}

// ---------------- combine: y[t] = obuf[pos0] + obuf[pos1] ----------------
__global__ void combine_kernel(const unsigned short* __restrict__ obuf,
                               const int* __restrict__ tok_pos,
                               float* __restrict__ y) {
  int idx = blockIdx.x * 256 + threadIdx.x;
  int t = idx >> 7;            // DIM/8 = 128 chunks per token
  int c = (idx & 127) << 3;
  int p0 = tok_pos[t * 2];
  int p1 = tok_pos[t * 2 + 1];
  uint4 a = *(const uint4*)(obuf + (size_t)p0 * DIM + c);
  uint4 b = *(const uint4*)(obuf + (size_t)p1 * DIM + c);
  float out[8];
  unsigned au[4] = {a.x, a.y, a.z, a.w};
  unsigned bu[4] = {b.x, b.y, b.z, b.w};
#pragma unroll
  for (int i = 0; i < 4; i++) {
    union { unsigned u; float f; } lo0, hi0, lo1, hi1;
    lo0.u = au[i] << 16; hi0.u = au[i] & 0xFFFF0000u;
    lo1.u = bu[i] << 16; hi1.u = bu[i] & 0xFFFF0000u;
    out[i * 2]     = lo0.f + lo1.f;
    out[i * 2 + 1] = hi0.f + hi1.f;
  }
  float* yp = y + (size_t)t * DIM + c;
  *(float4*)yp       = *(float4*)&out[0];
  *(float4*)(yp + 4) = *(float4*)&out[4];
}

// ---------------- launch: memset + 5 dispatches ----------------
extern "C" void kernel_launch(void* const* d_in, const int* in_sizes, int n_in,
                              void* d_out, int out_size, void* d_ws, size_t ws_size,
                              hipStream_t stream) {
  const float* x  = (const float*)d_in[0];
  const float* Wg = (const float*)d_in[1];
  const float* bg = (const float*)d_in[2];
  const float* W1 = (const float*)d_in[3];
  const float* b1 = (const float*)d_in[4];
  const float* W2 = (const float*)d_in[5];
  const float* b2 = (const float*)d_in[6];
  float* y = (float*)d_out;
  char* ws = (char*)d_ws;

  constexpr size_t OFF_META = 0;                                  // cnt@0, cnt2@64, seg@128
  constexpr size_t OFF_TOKE = 256;
  constexpr size_t OFF_TOKG = OFF_TOKE + (size_t)NTOK * 2 * 4;
  constexpr size_t OFF_TPOS = OFF_TOKG + (size_t)NTOK * 2 * 4;
  constexpr size_t OFF_TROW = OFF_TPOS + (size_t)NTOK * 2 * 4;
  constexpr size_t OFF_GROW = OFF_TROW + (size_t)CAP * 4;
  constexpr size_t OFF_ZB   = OFF_GROW + (size_t)CAP * 4;
  constexpr size_t OFF_XB   = OFF_ZB  + (size_t)DIM * 2;
  constexpr size_t OFF_W1T  = OFF_XB  + (size_t)NTOK * DIM * 2;
  constexpr size_t OFF_W2T  = OFF_W1T + (size_t)NE * DIM * HID * 2;
  constexpr size_t OFF_H    = OFF_W2T + (size_t)NE * DIM * HID * 2;
  // obuf aliases xb+w1t (both dead before gemm2 runs): needs CAP*DIM*2 = 35.7MB < 50.2MB
  constexpr size_t OFF_OBUF = OFF_XB;

  int* cnt        = (int*)(ws + OFF_META);
  int* cnt2       = (int*)(ws + OFF_META + 64);
  int* seg        = (int*)(ws + OFF_META + 128);
  int* tok_e      = (int*)(ws + OFF_TOKE);
  float* tok_g    = (float*)(ws + OFF_TOKG);
  int* tok_pos    = (int*)(ws + OFF_TPOS);
  int* token_row  = (int*)(ws + OFF_TROW);
  float* gate_row = (float*)(ws + OFF_GROW);
  unsigned short* zbuf = (unsigned short*)(ws + OFF_ZB);
  unsigned short* xb   = (unsigned short*)(ws + OFF_XB);
  unsigned short* w1t  = (unsigned short*)(ws + OFF_W1T);
  unsigned short* w2t  = (unsigned short*)(ws + OFF_W2T);
  unsigned short* hbuf = (unsigned short*)(ws + OFF_H);
  unsigned short* obuf = (unsigned short*)(ws + OFF_OBUF);

  // cnt/cnt2 must be zero BEFORE prep (gating atomicAdds in same dispatch as
  // any in-kernel zeroing would race). seg written by route.
  hipMemsetAsync(ws, 0, 192, stream);

  // prep: 1024 gating + 4096 W1-transpose + 4096 W2-transpose blocks
  prep_kernel<<<1024 + 8192, 256, 0, stream>>>(x, Wg, bg, W1, W2, w1t, w2t,
                                               tok_e, tok_g, xb, cnt, zbuf);
  route_kernel<<<NTOK / 256, 256, 0, stream>>>(tok_e, tok_g, cnt, cnt2, seg, token_row, gate_row, tok_pos);
  gemm1_kernel<<<dim3(HID / TN, CAP / TM), 256, 0, stream>>>(xb, w1t, b1, token_row, seg, zbuf, hbuf);
  gemm2_kernel<<<dim3(DIM / TN, CAP / TM), 256, 0, stream>>>(hbuf, w2t, b2, gate_row, seg, obuf);
  combine_kernel<<<NTOK * DIM / 8 / 256, 256, 0, stream>>>(obuf, tok_pos, y);
}